// Round 1
// baseline (712.400 us; speedup 1.0000x reference)
//
#include <hip/hip_runtime.h>
#include <hip/hip_bf16.h>

#define NEGINF -1e30f

__device__ __forceinline__ float fast_tanh(float x) {
    float e = __expf(fminf(2.f * x, 80.f));
    return (e - 1.f) * __builtin_amdgcn_rcpf(e + 1.f);
}
__device__ __forceinline__ float fast_sigmoid(float x) {
    return __builtin_amdgcn_rcpf(1.f + __expf(fminf(-x, 80.f)));
}

// ---------------- Tiled f32 GEMM: out[M,N] = A[M,K] @ W[N,K]^T + bias ----------------
// mode 0: plain bias. mode 1: out = sigmoid(acc+bias) * A[m, n]  (requires K == N)
__global__ __launch_bounds__(256) void gemm_bias(
    const float* __restrict__ A, const float* __restrict__ W,
    const float* __restrict__ bias, float* __restrict__ out,
    int M, int N, int K, int mode) {
    __shared__ __align__(16) float At[16][64];
    __shared__ __align__(16) float Wt[16][64];
    const int tid = threadIdx.x;
    const int n0 = blockIdx.x * 64;
    const int m0 = blockIdx.y * 64;
    const int tx = tid & 15;   // col group (4 cols)
    const int ty = tid >> 4;   // row group (4 rows)
    float acc[4][4];
#pragma unroll
    for (int r = 0; r < 4; r++)
#pragma unroll
        for (int c = 0; c < 4; c++) acc[r][c] = 0.f;

    const int lr = tid >> 2;          // 0..63 row within tile for loads
    const int lc = (tid & 3) * 4;     // 0..12 k within tile for loads

    for (int k0 = 0; k0 < K; k0 += 16) {
        float4 a = *(const float4*)(A + (size_t)(m0 + lr) * K + k0 + lc);
        float4 w = *(const float4*)(W + (size_t)(n0 + lr) * K + k0 + lc);
        At[lc + 0][lr] = a.x; At[lc + 1][lr] = a.y; At[lc + 2][lr] = a.z; At[lc + 3][lr] = a.w;
        Wt[lc + 0][lr] = w.x; Wt[lc + 1][lr] = w.y; Wt[lc + 2][lr] = w.z; Wt[lc + 3][lr] = w.w;
        __syncthreads();
#pragma unroll
        for (int kk = 0; kk < 16; kk++) {
            float4 av = *(const float4*)&At[kk][ty * 4];
            float4 wv = *(const float4*)&Wt[kk][tx * 4];
            const float* ap = (const float*)&av;
            const float* wp = (const float*)&wv;
#pragma unroll
            for (int r = 0; r < 4; r++)
#pragma unroll
                for (int c = 0; c < 4; c++) acc[r][c] += ap[r] * wp[c];
        }
        __syncthreads();
    }
    float4 bb = *(const float4*)(bias + n0 + tx * 4);
    const float* bp = (const float*)&bb;
#pragma unroll
    for (int r = 0; r < 4; r++) {
        int m = m0 + ty * 4 + r;
        float4 o;
        float* op = (float*)&o;
#pragma unroll
        for (int c = 0; c < 4; c++) op[c] = acc[r][c] + bp[c];
        if (mode == 1) {
            float4 av = *(const float4*)(A + (size_t)m * K + n0 + tx * 4);
            const float* ap = (const float*)&av;
#pragma unroll
            for (int c = 0; c < 4; c++) op[c] = fast_sigmoid(op[c]) * ap[c];
        }
        *(float4*)(out + (size_t)m * N + n0 + tx * 4) = o;
    }
}

// ---------------- Attention: scores(tanh-dot) -> masked softmax -> C = attn @ v ------
// Writes inp[b,q,:] = concat(v[b,q,:], C[b,q,:])   (inp is [B*L, 512])
__global__ __launch_bounds__(256) void attn_kernel(
    const float* __restrict__ v, const int* __restrict__ lengths,
    const float* __restrict__ own, const float* __restrict__ comp,
    const float* __restrict__ v_attn, float* __restrict__ inp) {
    const int L = 512, D = 256, H = 128;
    const int b = blockIdx.x >> 9;
    const int q = blockIdx.x & 511;
    const int tid = threadIdx.x;
    __shared__ float ownq[128];
    __shared__ float va[128];
    __shared__ float sc[512];
    __shared__ float red[256];
    if (tid < 128) {
        ownq[tid] = own[((size_t)(b * L + q)) * H + tid];
        va[tid] = v_attn[tid];
    }
    __syncthreads();
    const int len = lengths[b];
    float s2[2];
    float smax = NEGINF;
#pragma unroll
    for (int slot = 0; slot < 2; slot++) {
        int k = tid + slot * 256;
        float s = NEGINF;
        if (k < len) {
            const float* cp = comp + ((size_t)(b * L + k)) * H;
            s = 0.f;
#pragma unroll 4
            for (int h = 0; h < H; h += 4) {
                float4 c4 = *(const float4*)(cp + h);
                s += fast_tanh(ownq[h + 0] + c4.x) * va[h + 0];
                s += fast_tanh(ownq[h + 1] + c4.y) * va[h + 1];
                s += fast_tanh(ownq[h + 2] + c4.z) * va[h + 2];
                s += fast_tanh(ownq[h + 3] + c4.w) * va[h + 3];
            }
        }
        s2[slot] = s;
        smax = fmaxf(smax, s);
    }
    red[tid] = smax;
    __syncthreads();
    for (int off = 128; off > 0; off >>= 1) {
        if (tid < off) red[tid] = fmaxf(red[tid], red[tid + off]);
        __syncthreads();
    }
    float mx = red[0];
    __syncthreads();
    float lsum = 0.f;
#pragma unroll
    for (int slot = 0; slot < 2; slot++) {
        float e = __expf(s2[slot] - mx);
        sc[tid + slot * 256] = e;
        lsum += e;
    }
    red[tid] = lsum;
    __syncthreads();
    for (int off = 128; off > 0; off >>= 1) {
        if (tid < off) red[tid] += red[tid + off];
        __syncthreads();
    }
    float inv = __builtin_amdgcn_rcpf(red[0]);
    // context: thread tid owns output dim d = tid
    float a0 = 0.f, a1 = 0.f, a2 = 0.f, a3 = 0.f;
    const float* vb = v + ((size_t)b * L) * D + tid;
#pragma unroll 4
    for (int k = 0; k < L; k += 4) {
        a0 += sc[k + 0] * vb[(size_t)(k + 0) * D];
        a1 += sc[k + 1] * vb[(size_t)(k + 1) * D];
        a2 += sc[k + 2] * vb[(size_t)(k + 2) * D];
        a3 += sc[k + 3] * vb[(size_t)(k + 3) * D];
    }
    float accum = ((a0 + a1) + (a2 + a3)) * inv;
    size_t row = ((size_t)(b * L + q)) * 512;
    inp[row + 256 + tid] = accum;
    inp[row + tid] = v[((size_t)(b * L + q)) * D + tid];
}

// ---------------- Bidirectional GRU recurrence ----------------
// One block per (dir, batch). 768 threads: pair (j = tid>>1, half = tid&1) computes
// half of hp[j] = b_hh[j] + h . w_hh[j,:]; combined via shfl_xor.
__global__ __launch_bounds__(768, 2) void gru_kernel(
    const float* __restrict__ xp_f, const float* __restrict__ xp_b,
    const float* __restrict__ w_hh_f, const float* __restrict__ w_hh_b,
    const float* __restrict__ b_hh_f, const float* __restrict__ b_hh_b,
    const int* __restrict__ lengths, float* __restrict__ out) {
    const int L = 512, H = 128;
    const int dir = blockIdx.x >> 2;
    const int b = blockIdx.x & 3;
    const float* xp = dir ? xp_b : xp_f;
    const float* w_hh = dir ? w_hh_b : w_hh_f;
    const float* b_hh = dir ? b_hh_b : b_hh_f;
    const int tid = threadIdx.x;
    const int j = tid >> 1;
    const int half = tid & 1;
    __shared__ float h[128];
    __shared__ float hp[384];
    float4 wr[16];
    const float4* wrow = (const float4*)(w_hh + (size_t)j * H + half * 64);
#pragma unroll
    for (int i = 0; i < 16; i++) wr[i] = wrow[i];
    const float bj = (half == 0) ? b_hh[j] : 0.f;
    if (tid < 128) h[tid] = 0.f;
    const int len = lengths[b];
    const bool is_gate = (tid < 256) && (half == 0);
    const int jg = tid >> 1;
    __syncthreads();
    for (int stp = 0; stp < L; stp++) {
        int t = dir ? (L - 1 - stp) : stp;
        if (t >= len) {  // uniform per block
            if (tid < 128) out[((size_t)(b * L + t)) * 256 + dir * 128 + tid] = 0.f;
            continue;
        }
        float xr, xz, xn;
        if (is_gate) {  // prefetch input projections (independent of h)
            size_t base = ((size_t)(b * L + t)) * 384;
            xr = xp[base + jg];
            xz = xp[base + 128 + jg];
            xn = xp[base + 256 + jg];
        }
        float s = bj;
        const float4* h4 = ((const float4*)h) + half * 16;
#pragma unroll
        for (int i = 0; i < 16; i++) {
            float4 hh = h4[i];
            s += hh.x * wr[i].x + hh.y * wr[i].y + hh.z * wr[i].z + hh.w * wr[i].w;
        }
        s += __shfl_xor(s, 1);
        if (half == 0) hp[j] = s;
        __syncthreads();
        if (is_gate) {
            float r = fast_sigmoid(xr + hp[jg]);
            float z = fast_sigmoid(xz + hp[128 + jg]);
            float n = fast_tanh(xn + r * hp[256 + jg]);
            float hn = (1.f - z) * n + z * h[jg];
            h[jg] = hn;
            out[((size_t)(b * L + t)) * 256 + dir * 128 + jg] = hn;
        }
        __syncthreads();
    }
}

extern "C" void kernel_launch(void* const* d_in, const int* in_sizes, int n_in,
                              void* d_out, int out_size, void* d_ws, size_t ws_size,
                              hipStream_t stream) {
    const int B = 4, L = 512, D = 256, H = 128;
    const int M = B * L;  // 2048

    const float* v      = (const float*)d_in[0];
    const int* lengths  = (const int*)d_in[1];
    // d_in[2] = p_mask (bool) — unused, lengths is equivalent
    const float* own_W  = (const float*)d_in[3];
    const float* own_b  = (const float*)d_in[4];
    const float* comp_W = (const float*)d_in[5];
    const float* comp_b = (const float*)d_in[6];
    const float* v_attn = (const float*)d_in[7];
    const float* gate_W = (const float*)d_in[8];
    const float* gate_b = (const float*)d_in[9];
    const float* w_ih_f = (const float*)d_in[10];
    const float* w_hh_f = (const float*)d_in[11];
    const float* b_ih_f = (const float*)d_in[12];
    const float* b_hh_f = (const float*)d_in[13];
    const float* w_ih_b = (const float*)d_in[14];
    const float* w_hh_b = (const float*)d_in[15];
    const float* b_ih_b = (const float*)d_in[16];
    const float* b_hh_b = (const float*)d_in[17];

    float* ws   = (float*)d_ws;
    float* own  = ws;                       // [2048,128]
    float* comp = own + (size_t)M * H;      // [2048,128]
    float* inp  = comp + (size_t)M * H;     // [2048,512]
    float* gated = inp + (size_t)M * 512;   // [2048,512]
    float* xp_f = gated + (size_t)M * 512;  // [2048,384]
    float* xp_b = xp_f + (size_t)M * 384;   // [2048,384]
    float* out  = (float*)d_out;            // [2048,256]

    // 1/2: own & comp projections
    gemm_bias<<<dim3(H / 64, M / 64), 256, 0, stream>>>(v, own_W, own_b, own, M, H, D, 0);
    gemm_bias<<<dim3(H / 64, M / 64), 256, 0, stream>>>(v, comp_W, comp_b, comp, M, H, D, 0);
    // 3: attention -> inp = [v, C]
    attn_kernel<<<dim3(B * L), 256, 0, stream>>>(v, lengths, own, comp, v_attn, inp);
    // 4: gate
    gemm_bias<<<dim3(512 / 64, M / 64), 256, 0, stream>>>(inp, gate_W, gate_b, gated, M, 512, 512, 1);
    // 5/6: input projections for both GRU directions
    gemm_bias<<<dim3(384 / 64, M / 64), 256, 0, stream>>>(gated, w_ih_f, b_ih_f, xp_f, M, 384, 512, 0);
    gemm_bias<<<dim3(384 / 64, M / 64), 256, 0, stream>>>(gated, w_ih_b, b_ih_b, xp_b, M, 384, 512, 0);
    // 7: sequential GRU, one block per (dir, batch)
    gru_kernel<<<dim3(8), 768, 0, stream>>>(xp_f, xp_b, w_hh_f, w_hh_b, b_hh_f, b_hh_b, lengths, out);
}

// Round 2
// 635.793 us; speedup vs baseline: 1.1205x; 1.1205x over previous
//
#include <hip/hip_runtime.h>
#include <hip/hip_bf16.h>

#define NEGINF -1e30f

__device__ __forceinline__ float fast_tanh(float x) {
    float e = __expf(fminf(2.f * x, 80.f));
    return (e - 1.f) * __builtin_amdgcn_rcpf(e + 1.f);
}
__device__ __forceinline__ float fast_sigmoid(float x) {
    return __builtin_amdgcn_rcpf(1.f + __expf(fminf(-x, 80.f)));
}

// ---------------- Tiled f32 GEMM: out[M,N] = A[M,K] @ W[N,K]^T + bias ----------------
// Two weight/bias/out sets selectable by block tile (merges independent GEMMs sharing A).
// mode 0: plain bias. mode 1: out = sigmoid(acc+bias) * A[m, n]  (requires K == N)
__global__ __launch_bounds__(256) void gemm_bias(
    const float* __restrict__ A,
    const float* __restrict__ W1, const float* __restrict__ b1, float* __restrict__ out1,
    const float* __restrict__ W2, const float* __restrict__ b2, float* __restrict__ out2,
    int M, int N, int K, int nsplit, int mode) {
    __shared__ __align__(16) float At[16][64];
    __shared__ __align__(16) float Wt[16][64];
    const int tid = threadIdx.x;
    int bx = blockIdx.x;
    const float* W = W1; const float* bias = b1; float* out = out1;
    int n0;
    if (bx < nsplit) {
        n0 = bx * 64;
    } else {
        W = W2; bias = b2; out = out2;
        n0 = (bx - nsplit) * 64;
    }
    const int m0 = blockIdx.y * 64;
    const int tx = tid & 15;   // col group (4 cols)
    const int ty = tid >> 4;   // row group (4 rows)
    float acc[4][4];
#pragma unroll
    for (int r = 0; r < 4; r++)
#pragma unroll
        for (int c = 0; c < 4; c++) acc[r][c] = 0.f;

    const int lr = tid >> 2;          // 0..63 row within tile for loads
    const int lc = (tid & 3) * 4;     // 0..12 k within tile for loads

    for (int k0 = 0; k0 < K; k0 += 16) {
        float4 a = *(const float4*)(A + (size_t)(m0 + lr) * K + k0 + lc);
        float4 w = *(const float4*)(W + (size_t)(n0 + lr) * K + k0 + lc);
        At[lc + 0][lr] = a.x; At[lc + 1][lr] = a.y; At[lc + 2][lr] = a.z; At[lc + 3][lr] = a.w;
        Wt[lc + 0][lr] = w.x; Wt[lc + 1][lr] = w.y; Wt[lc + 2][lr] = w.z; Wt[lc + 3][lr] = w.w;
        __syncthreads();
#pragma unroll
        for (int kk = 0; kk < 16; kk++) {
            float4 av = *(const float4*)&At[kk][ty * 4];
            float4 wv = *(const float4*)&Wt[kk][tx * 4];
            const float* ap = (const float*)&av;
            const float* wp = (const float*)&wv;
#pragma unroll
            for (int r = 0; r < 4; r++)
#pragma unroll
                for (int c = 0; c < 4; c++) acc[r][c] += ap[r] * wp[c];
        }
        __syncthreads();
    }
    float4 bb = *(const float4*)(bias + n0 + tx * 4);
    const float* bp = (const float*)&bb;
#pragma unroll
    for (int r = 0; r < 4; r++) {
        int m = m0 + ty * 4 + r;
        float4 o;
        float* op = (float*)&o;
#pragma unroll
        for (int c = 0; c < 4; c++) op[c] = acc[r][c] + bp[c];
        if (mode == 1) {
            float4 av = *(const float4*)(A + (size_t)m * K + n0 + tx * 4);
            const float* ap = (const float*)&av;
#pragma unroll
            for (int c = 0; c < 4; c++) op[c] = fast_sigmoid(op[c]) * ap[c];
        }
        *(float4*)(out + (size_t)m * N + n0 + tx * 4) = o;
    }
}

// ---------------- Attention: scores(tanh-dot) -> masked softmax -> C = attn @ v ------
// Writes inp[b,q,:] = concat(v[b,q,:], C[b,q,:])   (inp is [B*L, 512])
__global__ __launch_bounds__(256) void attn_kernel(
    const float* __restrict__ v, const int* __restrict__ lengths,
    const float* __restrict__ own, const float* __restrict__ comp,
    const float* __restrict__ v_attn, float* __restrict__ inp) {
    const int L = 512, D = 256, H = 128;
    const int b = blockIdx.x >> 9;
    const int q = blockIdx.x & 511;
    const int tid = threadIdx.x;
    __shared__ float ownq[128];
    __shared__ float va[128];
    __shared__ float sc[512];
    __shared__ float red[256];
    if (tid < 128) {
        ownq[tid] = own[((size_t)(b * L + q)) * H + tid];
        va[tid] = v_attn[tid];
    }
    __syncthreads();
    const int len = lengths[b];
    float s2[2];
    float smax = NEGINF;
#pragma unroll
    for (int slot = 0; slot < 2; slot++) {
        int k = tid + slot * 256;
        float s = NEGINF;
        if (k < len) {
            const float* cp = comp + ((size_t)(b * L + k)) * H;
            s = 0.f;
#pragma unroll 4
            for (int h = 0; h < H; h += 4) {
                float4 c4 = *(const float4*)(cp + h);
                s += fast_tanh(ownq[h + 0] + c4.x) * va[h + 0];
                s += fast_tanh(ownq[h + 1] + c4.y) * va[h + 1];
                s += fast_tanh(ownq[h + 2] + c4.z) * va[h + 2];
                s += fast_tanh(ownq[h + 3] + c4.w) * va[h + 3];
            }
        }
        s2[slot] = s;
        smax = fmaxf(smax, s);
    }
    red[tid] = smax;
    __syncthreads();
    for (int off = 128; off > 0; off >>= 1) {
        if (tid < off) red[tid] = fmaxf(red[tid], red[tid + off]);
        __syncthreads();
    }
    float mx = red[0];
    __syncthreads();
    float lsum = 0.f;
#pragma unroll
    for (int slot = 0; slot < 2; slot++) {
        float e = __expf(s2[slot] - mx);
        sc[tid + slot * 256] = e;
        lsum += e;
    }
    red[tid] = lsum;
    __syncthreads();
    for (int off = 128; off > 0; off >>= 1) {
        if (tid < off) red[tid] += red[tid + off];
        __syncthreads();
    }
    float inv = __builtin_amdgcn_rcpf(red[0]);
    // context: thread tid owns output dim d = tid
    float a0 = 0.f, a1 = 0.f, a2 = 0.f, a3 = 0.f;
    const float* vb = v + ((size_t)b * L) * D + tid;
#pragma unroll 4
    for (int k = 0; k < L; k += 4) {
        a0 += sc[k + 0] * vb[(size_t)(k + 0) * D];
        a1 += sc[k + 1] * vb[(size_t)(k + 1) * D];
        a2 += sc[k + 2] * vb[(size_t)(k + 2) * D];
        a3 += sc[k + 3] * vb[(size_t)(k + 3) * D];
    }
    float accum = ((a0 + a1) + (a2 + a3)) * inv;
    size_t row = ((size_t)(b * L + q)) * 512;
    inp[row + 256 + tid] = accum;
    inp[row + tid] = v[((size_t)(b * L + q)) * D + tid];
}

// ---------------- Bidirectional GRU recurrence ----------------
// One block per (dir, batch). 768 threads: pair (j = tid>>1, half = tid&1) computes
// half of hp[j] = b_hh[j] + h . w_hh[j,:]. Halves combined via LDS (hp0/hp1), not shfl.
// 8 independent FMA accumulator chains; out store deferred past the barrier so its
// vmcnt drain overlaps the next step's dot phase. Only len steps run (tail pre-zeroed).
__global__ __launch_bounds__(768, 3) void gru_kernel(
    const float* __restrict__ xp_f, const float* __restrict__ xp_b,
    const float* __restrict__ w_hh_f, const float* __restrict__ w_hh_b,
    const float* __restrict__ b_hh_f, const float* __restrict__ b_hh_b,
    const int* __restrict__ lengths, float* __restrict__ out) {
    const int L = 512, H = 128;
    const int dir = blockIdx.x >> 2;
    const int b = blockIdx.x & 3;
    const float* xp = dir ? xp_b : xp_f;
    const float* w_hh = dir ? w_hh_b : w_hh_f;
    const float* b_hh = dir ? b_hh_b : b_hh_f;
    const int tid = threadIdx.x;
    const int j = tid >> 1;
    const int half = tid & 1;
    __shared__ float h[128];
    __shared__ float hp0[384];
    __shared__ float hp1[384];
    // weights for this thread's half-row, in registers (16 float4 = 64 VGPR)
    float4 wr[16];
    const float4* wrow = (const float4*)(w_hh + (size_t)j * H + half * 64);
#pragma unroll
    for (int i = 0; i < 16; i++) wr[i] = wrow[i];
    const float bj = (half == 0) ? b_hh[j] : 0.f;

    const int len = lengths[b];
    // pre-zero masked tail: out[b, t, dir*128 + jj] = 0 for t in [len, L)
    for (int idx = tid; idx < (L - len) * 128; idx += 768) {
        int tt = len + (idx >> 7);
        int jj = idx & 127;
        out[((size_t)(b * L + tt)) * 256 + dir * 128 + jj] = 0.f;
    }
    if (tid < 128) h[tid] = 0.f;
    float hcur = 0.f;   // gate thread's own h[tid]
    __syncthreads();

    const float4* h4 = ((const float4*)h) + half * 16;
    for (int stp = 0; stp < len; stp++) {
        const int t = dir ? (len - 1 - stp) : stp;
        float xr, xz, xn;
        if (tid < 128) {  // gate threads prefetch input projections (independent of h)
            size_t base = ((size_t)(b * L + t)) * 384;
            xr = xp[base + tid];
            xz = xp[base + 128 + tid];
            xn = xp[base + 256 + tid];
        }
        // half-dot: 8 independent accumulator chains (8 serial FMAs each)
        float a0 = 0.f, a1 = 0.f, a2 = 0.f, a3 = 0.f;
        float a4 = 0.f, a5 = 0.f, a6 = 0.f, a7 = 0.f;
#pragma unroll
        for (int i = 0; i < 16; i += 2) {
            float4 h0 = h4[i];
            float4 h1 = h4[i + 1];
            a0 += h0.x * wr[i].x; a1 += h0.y * wr[i].y;
            a2 += h0.z * wr[i].z; a3 += h0.w * wr[i].w;
            a4 += h1.x * wr[i + 1].x; a5 += h1.y * wr[i + 1].y;
            a6 += h1.z * wr[i + 1].z; a7 += h1.w * wr[i + 1].w;
        }
        float s = (((a0 + a4) + (a1 + a5)) + ((a2 + a6) + (a3 + a7))) + bj;
        if (half == 0) hp0[j] = s; else hp1[j] = s;
        __syncthreads();   // hp ready; all reads of h done
        float hn;
        if (tid < 128) {
            float hr = hp0[tid] + hp1[tid];
            float hz = hp0[128 + tid] + hp1[128 + tid];
            float hh = hp0[256 + tid] + hp1[256 + tid];
            float r = fast_sigmoid(xr + hr);
            float z = fast_sigmoid(xz + hz);
            float n = fast_tanh(xn + r * hh);
            hn = (1.f - z) * n + z * hcur;
            hcur = hn;
            h[tid] = hn;
        }
        __syncthreads();   // h ready
        if (tid < 128) {   // fire-and-forget; drains during next step's dot phase
            out[((size_t)(b * L + t)) * 256 + dir * 128 + tid] = hn;
        }
    }
}

extern "C" void kernel_launch(void* const* d_in, const int* in_sizes, int n_in,
                              void* d_out, int out_size, void* d_ws, size_t ws_size,
                              hipStream_t stream) {
    const int B = 4, L = 512, D = 256, H = 128;
    const int M = B * L;  // 2048

    const float* v      = (const float*)d_in[0];
    const int* lengths  = (const int*)d_in[1];
    // d_in[2] = p_mask (bool) — unused, lengths is equivalent
    const float* own_W  = (const float*)d_in[3];
    const float* own_b  = (const float*)d_in[4];
    const float* comp_W = (const float*)d_in[5];
    const float* comp_b = (const float*)d_in[6];
    const float* v_attn = (const float*)d_in[7];
    const float* gate_W = (const float*)d_in[8];
    const float* gate_b = (const float*)d_in[9];
    const float* w_ih_f = (const float*)d_in[10];
    const float* w_hh_f = (const float*)d_in[11];
    const float* b_ih_f = (const float*)d_in[12];
    const float* b_hh_f = (const float*)d_in[13];
    const float* w_ih_b = (const float*)d_in[14];
    const float* w_hh_b = (const float*)d_in[15];
    const float* b_ih_b = (const float*)d_in[16];
    const float* b_hh_b = (const float*)d_in[17];

    float* ws   = (float*)d_ws;
    float* own  = ws;                       // [2048,128]
    float* comp = own + (size_t)M * H;      // [2048,128]
    float* inp  = comp + (size_t)M * H;     // [2048,512]
    float* gated = inp + (size_t)M * 512;   // [2048,512]
    float* xp_f = gated + (size_t)M * 512;  // [2048,384]
    float* xp_b = xp_f + (size_t)M * 384;   // [2048,384]
    float* out  = (float*)d_out;            // [2048,256]

    // 1: own & comp projections in one launch (tiles 0..1 -> own, 2..3 -> comp)
    gemm_bias<<<dim3(4, M / 64), 256, 0, stream>>>(
        v, own_W, own_b, own, comp_W, comp_b, comp, M, H, D, 2, 0);
    // 2: attention -> inp = [v, C]
    attn_kernel<<<dim3(B * L), 256, 0, stream>>>(v, lengths, own, comp, v_attn, inp);
    // 3: gate
    gemm_bias<<<dim3(8, M / 64), 256, 0, stream>>>(
        inp, gate_W, gate_b, gated, gate_W, gate_b, gated, M, 512, 512, 8, 1);
    // 4: input projections for both GRU directions in one launch
    gemm_bias<<<dim3(12, M / 64), 256, 0, stream>>>(
        gated, w_ih_f, b_ih_f, xp_f, w_ih_b, b_ih_b, xp_b, M, 384, 512, 6, 0);
    // 5: sequential GRU, one block per (dir, batch)
    gru_kernel<<<dim3(8), 768, 0, stream>>>(xp_f, xp_b, w_hh_f, w_hh_b, b_hh_f, b_hh_b, lengths, out);
}